// Round 21
// baseline (140.858 us; speedup 1.0000x reference)
//
#include <hip/hip_runtime.h>

typedef __attribute__((ext_vector_type(8))) short short8;
typedef __attribute__((ext_vector_type(4))) float f32x4;

#define BB 64
#define TS 2000
#define NN (TS*160)
#define MB 63            // 63 outputs/block: 64 hid rows = 63 + 1 halo
#define TB 32            // ceil(2000/63)
#define NTH 640          // 10 waves: wave = output col-tile ct
#define EPS_LOG 1.52587890625e-05f   // 2^-16

// ws layout: ushort (bf16) region then float region, then hid buffer
#define W1F_U 0          // 40960 ushorts: [tap][ct10][kp16][col16][8]
#define W1T_U 40960      // 20480 ushorts: [tap][ct10][kp8][col16][8]  (MEAN-FOLDED W1teff; k>=40 zero)
#define W2_U  61440      // 51200 ushorts: [tap][ct10][kp20][col16][8]
#define B1C_F 56320      // float idx: b1f+b1t (160)
#define B2C_F 56480      // float idx: b2 (160)
#define HID_U 113664     // ushort idx: hid[64][2001][160] bf16; row p = t+1 (row 0 = zeros)
#define WS_NEED (227328ull + (unsigned long long)BB*2001*160*2)

__device__ __forceinline__ unsigned short f2bf(float f) {
    union { float f; unsigned u; } v; v.f = f;
    unsigned r = v.u + 0x7FFF + ((v.u >> 16) & 1);   // RNE
    return (unsigned short)(r >> 16);
}

__global__ void repack(const float* __restrict__ W1f, const float* __restrict__ b1f,
                       const float* __restrict__ W1t, const float* __restrict__ b1t,
                       const float* __restrict__ W2,  const float* __restrict__ b2,
                       void* wsv) {
    unsigned short* wu = (unsigned short*)wsv;
    float* wf = (float*)wsv;
    int n = blockIdx.x * 256 + threadIdx.x;
    if (n < 40960) {                       // W1f
        int tap = n / 20480, m = n % 20480;
        int ct = m / 2048, m2 = m % 2048;
        int kp = m2 / 128, col = (m2 % 128) / 8, i = m2 % 8;
        int o = ct * 16 + col, c = kp * 8 + i;
        wu[W1F_U + n] = f2bf(W1f[(o * 128 + c) * 2 + tap]);
    } else if (n < 61440) {                // W1teff: mean-folded, K padded to 64
        int r = n - 40960;
        int tap = r / 10240, m = r % 10240;
        int ct = m / 1024, m2 = m % 1024;
        int kp = m2 / 128, col = (m2 % 128) / 8, i = m2 % 8;
        int o = ct * 16 + col, c = kp * 8 + i;
        unsigned short v = 0;
        if (c < 40) {
            float S = 0.f;
            for (int g = 0; g < 40; ++g) S += W1t[(o * 41 + g) * 2 + tap];
            float w40 = W1t[(o * 41 + 40) * 2 + tap];
            v = f2bf(W1t[(o * 41 + c) * 2 + tap] + (w40 - S) * 0.025f);
        }
        wu[W1T_U + r] = v;
    } else if (n < 112640) {               // W2
        int r = n - 61440;
        int tap = r / 25600, m = r % 25600;
        int ct = m / 2560, m2 = m % 2560;
        int kp = m2 / 128, col = (m2 % 128) / 8, i = m2 % 8;
        int o = ct * 16 + col, c = kp * 8 + i;
        wu[W2_U + r] = f2bf(W2[(o * 160 + c) * 2 + tap]);
    } else if (n < 112800) {               // b1 combined
        int o = n - 112640;
        wf[B1C_F + o] = b1f[o] + b1t[o];
    } else if (n < 112960) {               // b2 copy
        int o = n - 112800;
        wf[B2C_F + o] = b2[o];
    }
}

// ================= split kernel 1: hid producer (stage feat/e -> B) =================
__global__ __launch_bounds__(NTH, 5) void td_hid(
    const float* __restrict__ x,
    const float* __restrict__ feat,
    const unsigned short* __restrict__ wu,
    const float* __restrict__ wf,
    unsigned short* __restrict__ hid)
{
    __shared__ __align__(16) unsigned short s_feat[65 * 136];
    __shared__ __align__(16) unsigned short s_e   [65 * 72];  // cols 0..39 = e, 40..63 zero

    const int tid  = threadIdx.x;
    const int b    = blockIdx.y;
    const int t0   = blockIdx.x * MB;
    const int wid  = tid >> 6;    // 0..9 = ct
    const int lane = tid & 63;
    const int lr   = lane & 15;
    const int lk   = lane >> 4;
    const int ct   = wid;
    const int cbase = lk * 8;

    const float4* feat4 = (const float4*)feat;
    const float4* x4    = (const float4*)x;

    short8 w0[6], w1[6];
    {
        const unsigned short* bf0 = wu + W1F_U + ct * 2048 + lk * 128 + lr * 8;
        const unsigned short* bt0 = wu + W1T_U + ct * 1024 + lk * 128 + lr * 8;
#pragma unroll
        for (int s = 0; s < 4; ++s) {
            w0[s] = *(const short8*)(bf0 + s * 512);
            w1[s] = *(const short8*)(bf0 + 20480 + s * 512);
        }
#pragma unroll
        for (int s = 0; s < 2; ++s) {
            w0[4 + s] = *(const short8*)(bt0 + s * 512);
            w1[4 + s] = *(const short8*)(bt0 + 10240 + s * 512);
        }
    }
    const float4 bias1 = *(const float4*)&wf[B1C_F + ct * 16 + lk * 4];

    for (int idx = tid; idx < 65 * 32; idx += NTH) {
        int r = idx >> 5, c4 = idx & 31;
        int t = t0 - 2 + r;
        float4 v = make_float4(0.f, 0.f, 0.f, 0.f);
        if (t >= 0 && t < TS) v = feat4[((size_t)b * TS + t) * 32 + c4];
        ushort4 h;
        h.x = f2bf(v.x); h.y = f2bf(v.y); h.z = f2bf(v.z); h.w = f2bf(v.w);
        *(ushort4*)&s_feat[r * 136 + c4 * 4] = h;
    }
    for (int idx = tid; idx < 65 * 40; idx += NTH) {
        int r = idx / 40, g = idx - r * 40;
        int t = t0 - 2 + r;
        unsigned short u = 0;
        if (t >= 0 && t < TS) {
            float4 v = x4[((size_t)b * NN + (size_t)t * 160 + g * 4) >> 2];
            float m = 0.25f * (fabsf(v.x) + fabsf(v.y) + fabsf(v.z) + fabsf(v.w));
            u = f2bf(__logf(m + EPS_LOG));
        }
        s_e[r * 72 + g] = u;
    }
    if (tid < 65 * 3) {
        int r = tid / 3, sgm = tid - r * 3;
        short8 z = {0, 0, 0, 0, 0, 0, 0, 0};
        *(short8*)&s_e[r * 72 + 40 + sgm * 8] = z;
    }
    __syncthreads();   // the ONLY barrier

#pragma unroll 2
    for (int tile = 0; tile < 4; ++tile) {
        const int rB = tile * 16 + lr;
        const unsigned short* f0 = &s_feat[rB * 136 + cbase];
        const unsigned short* e0 = &s_e[rB * 72 + cbase];
        f32x4 acc0 = {0.f, 0.f, 0.f, 0.f};
        f32x4 acc1 = {0.f, 0.f, 0.f, 0.f};
#pragma unroll
        for (int s = 0; s < 4; ++s) {
            short8 a0 = *(const short8*)(f0 + 32 * s);          // feat[t-1]
            short8 a1 = *(const short8*)(f0 + 136 + 32 * s);    // feat[t]
            acc0 = __builtin_amdgcn_mfma_f32_16x16x32_bf16(w0[s], a0, acc0, 0, 0, 0);
            acc1 = __builtin_amdgcn_mfma_f32_16x16x32_bf16(w1[s], a1, acc1, 0, 0, 0);
        }
#pragma unroll
        for (int s = 0; s < 2; ++s) {
            short8 a0 = *(const short8*)(e0 + 32 * s);
            short8 a1 = *(const short8*)(e0 + 72 + 32 * s);
            acc0 = __builtin_amdgcn_mfma_f32_16x16x32_bf16(w0[4 + s], a0, acc0, 0, 0, 0);
            acc1 = __builtin_amdgcn_mfma_f32_16x16x32_bf16(w1[4 + s], a1, acc1, 0, 0, 0);
        }
        const int th = t0 - 1 + rB;   // lane-uniform; hid row p = th+1
        ushort4 pk;
        {
            float v0 = acc0[0] + acc1[0] + bias1.x; v0 = v0 >= 0.f ? v0 : 0.2f * v0;
            float v1 = acc0[1] + acc1[1] + bias1.y; v1 = v1 >= 0.f ? v1 : 0.2f * v1;
            float v2 = acc0[2] + acc1[2] + bias1.z; v2 = v2 >= 0.f ? v2 : 0.2f * v2;
            float v3 = acc0[3] + acc1[3] + bias1.w; v3 = v3 >= 0.f ? v3 : 0.2f * v3;
            pk.x = f2bf(v0); pk.y = f2bf(v1); pk.z = f2bf(v2); pk.w = f2bf(v3);
        }
        if (th < 0) pk = make_ushort4(0, 0, 0, 0);   // row 0 = zeros (causal pad)
        if (th < TS) {
            size_t off = ((size_t)b * 2001 + (th + 1)) * 160 + ct * 16 + lk * 4;
            *(ushort4*)&hid[off] = pk;   // boundary rows double-written w/ identical data
        }
    }
}

// ============ split kernel 2: consumer — NO LDS, NO barriers ============
__global__ __launch_bounds__(NTH) void td_out(
    const float* __restrict__ x,
    const unsigned short* __restrict__ hid,
    const unsigned short* __restrict__ wu,
    const float* __restrict__ wf,
    float* __restrict__ out)
{
    const int tid  = threadIdx.x;
    const int b    = blockIdx.y;
    const int t0   = blockIdx.x * MB;
    const int wid  = tid >> 6;    // 0..9 = ct
    const int lane = tid & 63;
    const int lr   = lane & 15;
    const int lk   = lane >> 4;
    const int ct   = wid;
    const int cbase = lk * 8;

    short8 w0[5], w1[5];
    {
        const unsigned short* b2p = wu + W2_U + ct * 2560 + lk * 128 + lr * 8;
#pragma unroll
        for (int s = 0; s < 5; ++s) {
            w0[s] = *(const short8*)(b2p + s * 512);
            w1[s] = *(const short8*)(b2p + 25600 + s * 512);
        }
    }
    const float4 bias2 = *(const float4*)&wf[B2C_F + ct * 16 + lk * 4];

#pragma unroll 2
    for (int tile = 0; tile < 4; ++tile) {
        const int rC = tile * 16 + lr;
        const int t  = t0 + rC;               // lane-uniform
        const int tc = t < TS ? t : TS - 1;   // clamp OOB lanes' load addresses
        // hid[t-1] = padded row tc; hid[t] = padded row tc+1 (both <= 2000)
        const unsigned short* p0 = hid + ((size_t)b * 2001 + tc) * 160 + cbase;
        f32x4 acc0 = {0.f, 0.f, 0.f, 0.f};
        f32x4 acc1 = {0.f, 0.f, 0.f, 0.f};
#pragma unroll
        for (int s = 0; s < 5; ++s) {
            short8 a0 = *(const short8*)(p0 + 32 * s);          // hid[t-1]
            short8 a1 = *(const short8*)(p0 + 160 + 32 * s);    // hid[t]
            acc0 = __builtin_amdgcn_mfma_f32_16x16x32_bf16(w0[s], a0, acc0, 0, 0, 0);
            acc1 = __builtin_amdgcn_mfma_f32_16x16x32_bf16(w1[s], a1, acc1, 0, 0, 0);
        }
        if (rC < MB && t < TS) {
            size_t off = (size_t)b * NN + (size_t)t * 160 + ct * 16 + lk * 4;
            float4 xv = *(const float4*)&x[off];
            float4 yv;
            yv.x = __expf(acc0[0] + acc1[0] + bias2.x) * xv.x;
            yv.y = __expf(acc0[1] + acc1[1] + bias2.y) * xv.y;
            yv.z = __expf(acc0[2] + acc1[2] + bias2.z) * xv.z;
            yv.w = __expf(acc0[3] + acc1[3] + bias2.w) * xv.w;
            *(float4*)&out[off] = yv;
        }
    }
}

// ================= fallback: r19 monolithic kernel (verbatim) =================
__global__ __launch_bounds__(NTH, 5) void td_mono(
    const float* __restrict__ x,
    const float* __restrict__ feat,
    const unsigned short* __restrict__ wu,
    const float* __restrict__ wf,
    float* __restrict__ out)
{
    __shared__ __align__(16) unsigned short s_feat[65 * 136];
    __shared__ __align__(16) unsigned short s_e   [65 * 72];
    __shared__ __align__(16) unsigned short s_hid [64 * 168];

    const int tid  = threadIdx.x;
    const int b    = blockIdx.y;
    const int t0   = blockIdx.x * MB;
    const int wid  = tid >> 6;
    const int lane = tid & 63;
    const int lr   = lane & 15;
    const int lk   = lane >> 4;
    const int ct   = wid;
    const int cbase = lk * 8;

    const float4* feat4 = (const float4*)feat;
    const float4* x4    = (const float4*)x;

    short8 w0[6], w1[6];
    {
        const unsigned short* bf0 = wu + W1F_U + ct * 2048 + lk * 128 + lr * 8;
        const unsigned short* bt0 = wu + W1T_U + ct * 1024 + lk * 128 + lr * 8;
#pragma unroll
        for (int s = 0; s < 4; ++s) {
            w0[s] = *(const short8*)(bf0 + s * 512);
            w1[s] = *(const short8*)(bf0 + 20480 + s * 512);
        }
#pragma unroll
        for (int s = 0; s < 2; ++s) {
            w0[4 + s] = *(const short8*)(bt0 + s * 512);
            w1[4 + s] = *(const short8*)(bt0 + 10240 + s * 512);
        }
    }
    const float4 bias1 = *(const float4*)&wf[B1C_F + ct * 16 + lk * 4];

    for (int idx = tid; idx < 65 * 32; idx += NTH) {
        int r = idx >> 5, c4 = idx & 31;
        int t = t0 - 2 + r;
        float4 v = make_float4(0.f, 0.f, 0.f, 0.f);
        if (t >= 0 && t < TS) v = feat4[((size_t)b * TS + t) * 32 + c4];
        ushort4 h;
        h.x = f2bf(v.x); h.y = f2bf(v.y); h.z = f2bf(v.z); h.w = f2bf(v.w);
        *(ushort4*)&s_feat[r * 136 + c4 * 4] = h;
    }
    for (int idx = tid; idx < 65 * 40; idx += NTH) {
        int r = idx / 40, g = idx - r * 40;
        int t = t0 - 2 + r;
        unsigned short u = 0;
        if (t >= 0 && t < TS) {
            float4 v = x4[((size_t)b * NN + (size_t)t * 160 + g * 4) >> 2];
            float m = 0.25f * (fabsf(v.x) + fabsf(v.y) + fabsf(v.z) + fabsf(v.w));
            u = f2bf(__logf(m + EPS_LOG));
        }
        s_e[r * 72 + g] = u;
    }
    if (tid < 65 * 3) {
        int r = tid / 3, sgm = tid - r * 3;
        short8 z = {0, 0, 0, 0, 0, 0, 0, 0};
        *(short8*)&s_e[r * 72 + 40 + sgm * 8] = z;
    }
    __syncthreads();

#pragma unroll 2
    for (int tile = 0; tile < 4; ++tile) {
        const int rB = tile * 16 + lr;
        const unsigned short* f0 = &s_feat[rB * 136 + cbase];
        const unsigned short* e0 = &s_e[rB * 72 + cbase];
        f32x4 acc0 = {0.f, 0.f, 0.f, 0.f};
        f32x4 acc1 = {0.f, 0.f, 0.f, 0.f};
#pragma unroll
        for (int s = 0; s < 4; ++s) {
            short8 a0 = *(const short8*)(f0 + 32 * s);
            short8 a1 = *(const short8*)(f0 + 136 + 32 * s);
            acc0 = __builtin_amdgcn_mfma_f32_16x16x32_bf16(w0[s], a0, acc0, 0, 0, 0);
            acc1 = __builtin_amdgcn_mfma_f32_16x16x32_bf16(w1[s], a1, acc1, 0, 0, 0);
        }
#pragma unroll
        for (int s = 0; s < 2; ++s) {
            short8 a0 = *(const short8*)(e0 + 32 * s);
            short8 a1 = *(const short8*)(e0 + 72 + 32 * s);
            acc0 = __builtin_amdgcn_mfma_f32_16x16x32_bf16(w0[4 + s], a0, acc0, 0, 0, 0);
            acc1 = __builtin_amdgcn_mfma_f32_16x16x32_bf16(w1[4 + s], a1, acc1, 0, 0, 0);
        }
        const int th = t0 - 1 + rB;
        ushort4 pk;
        {
            float v0 = acc0[0] + acc1[0] + bias1.x; v0 = v0 >= 0.f ? v0 : 0.2f * v0;
            float v1 = acc0[1] + acc1[1] + bias1.y; v1 = v1 >= 0.f ? v1 : 0.2f * v1;
            float v2 = acc0[2] + acc1[2] + bias1.z; v2 = v2 >= 0.f ? v2 : 0.2f * v2;
            float v3 = acc0[3] + acc1[3] + bias1.w; v3 = v3 >= 0.f ? v3 : 0.2f * v3;
            pk.x = f2bf(v0); pk.y = f2bf(v1); pk.z = f2bf(v2); pk.w = f2bf(v3);
        }
        if (th < 0) pk = make_ushort4(0, 0, 0, 0);
        *(ushort4*)&s_hid[rB * 168 + ct * 16 + lk * 4] = pk;
    }

    __builtin_amdgcn_sched_barrier(0);

    short8 wc0[5], wc1[5];
    {
        const unsigned short* b2p = wu + W2_U + ct * 2560 + lk * 128 + lr * 8;
#pragma unroll
        for (int s = 0; s < 5; ++s) {
            wc0[s] = *(const short8*)(b2p + s * 512);
            wc1[s] = *(const short8*)(b2p + 25600 + s * 512);
        }
    }
    const float4 bias2 = *(const float4*)&wf[B2C_F + ct * 16 + lk * 4];

    __syncthreads();

#pragma unroll
    for (int tile = 0; tile < 4; ++tile) {
        const int rC  = tile * 16 + lr;
        const int rCc = rC < 63 ? rC : 62;
        const unsigned short* hb = &s_hid[rCc * 168 + cbase];
        f32x4 acc0 = {0.f, 0.f, 0.f, 0.f};
        f32x4 acc1 = {0.f, 0.f, 0.f, 0.f};
#pragma unroll
        for (int s = 0; s < 5; ++s) {
            short8 a0 = *(const short8*)(hb + 32 * s);
            short8 a1 = *(const short8*)(hb + 168 + 32 * s);
            acc0 = __builtin_amdgcn_mfma_f32_16x16x32_bf16(wc0[s], a0, acc0, 0, 0, 0);
            acc1 = __builtin_amdgcn_mfma_f32_16x16x32_bf16(wc1[s], a1, acc1, 0, 0, 0);
        }
        const int t = t0 + rC;
        if (rC < MB && t < TS) {
            size_t off = (size_t)b * NN + (size_t)t * 160 + ct * 16 + lk * 4;
            float4 xv = *(const float4*)&x[off];
            float4 yv;
            yv.x = __expf(acc0[0] + acc1[0] + bias2.x) * xv.x;
            yv.y = __expf(acc0[1] + acc1[1] + bias2.y) * xv.y;
            yv.z = __expf(acc0[2] + acc1[2] + bias2.z) * xv.z;
            yv.w = __expf(acc0[3] + acc1[3] + bias2.w) * xv.w;
            *(float4*)&out[off] = yv;
        }
    }
}

extern "C" void kernel_launch(void* const* d_in, const int* in_sizes, int n_in,
                              void* d_out, int out_size, void* d_ws, size_t ws_size,
                              hipStream_t stream) {
    const float* x    = (const float*)d_in[0];
    const float* feat = (const float*)d_in[1];
    const float* W1f  = (const float*)d_in[2];
    const float* b1f  = (const float*)d_in[3];
    const float* W1t  = (const float*)d_in[4];
    const float* b1t  = (const float*)d_in[5];
    const float* W2   = (const float*)d_in[6];
    const float* b2   = (const float*)d_in[7];
    float* out = (float*)d_out;
    unsigned short* wu = (unsigned short*)d_ws;
    const float* wf    = (const float*)d_ws;

    repack<<<(112960 + 255) / 256, 256, 0, stream>>>(W1f, b1f, W1t, b1t, W2, b2, d_ws);

    if (ws_size >= WS_NEED) {
        unsigned short* hid = wu + HID_U;
        td_hid<<<dim3(TB, BB), NTH, 0, stream>>>(x, feat, wu, wf, hid);
        td_out<<<dim3(TB, BB), NTH, 0, stream>>>(x, hid, wu, wf, out);
    } else {
        td_mono<<<dim3(TB, BB), NTH, 0, stream>>>(x, feat, wu, wf, out);
    }
}

// Round 22
// 81.890 us; speedup vs baseline: 1.7201x; 1.7201x over previous
//
#include <hip/hip_runtime.h>

typedef __attribute__((ext_vector_type(8))) short short8;
typedef __attribute__((ext_vector_type(4))) float f32x4;

#define BB 64
#define TS 2000
#define NN (TS*160)
#define MB 63            // 63 outputs/tile: 64 hid rows = 63 + 1 halo
#define TPB 4            // time-tiles per block (pipelined)
#define GX 8             // grid.x: 8 * 4 = 32 tiles = ceil(2000/63)
#define NTH 640          // 10 waves: wave = output col-tile ct
#define EPS_LOG 1.52587890625e-05f   // 2^-16

// ws layout: ushort (bf16) region then float region
#define W1F_U 0          // 40960 ushorts: [tap][ct10][kp16][col16][8]
#define W1T_U 40960      // 20480 ushorts: [tap][ct10][kp8][col16][8]  (MEAN-FOLDED W1teff; k>=40 zero)
#define W2_U  61440      // 51200 ushorts: [tap][ct10][kp20][col16][8]
#define B1C_F 56320      // float idx: b1f+b1t (160)
#define B2C_F 56480      // float idx: b2 (160)

__device__ __forceinline__ unsigned short f2bf(float f) {
    union { float f; unsigned u; } v; v.f = f;
    unsigned r = v.u + 0x7FFF + ((v.u >> 16) & 1);   // RNE
    return (unsigned short)(r >> 16);
}

__global__ void repack(const float* __restrict__ W1f, const float* __restrict__ b1f,
                       const float* __restrict__ W1t, const float* __restrict__ b1t,
                       const float* __restrict__ W2,  const float* __restrict__ b2,
                       void* wsv) {
    unsigned short* wu = (unsigned short*)wsv;
    float* wf = (float*)wsv;
    int n = blockIdx.x * 256 + threadIdx.x;
    if (n < 40960) {                       // W1f
        int tap = n / 20480, m = n % 20480;
        int ct = m / 2048, m2 = m % 2048;
        int kp = m2 / 128, col = (m2 % 128) / 8, i = m2 % 8;
        int o = ct * 16 + col, c = kp * 8 + i;
        wu[W1F_U + n] = f2bf(W1f[(o * 128 + c) * 2 + tap]);
    } else if (n < 61440) {                // W1teff: mean-folded, K padded to 64
        int r = n - 40960;
        int tap = r / 10240, m = r % 10240;
        int ct = m / 1024, m2 = m % 1024;
        int kp = m2 / 128, col = (m2 % 128) / 8, i = m2 % 8;
        int o = ct * 16 + col, c = kp * 8 + i;
        unsigned short v = 0;
        if (c < 40) {
            float S = 0.f;
            for (int g = 0; g < 40; ++g) S += W1t[(o * 41 + g) * 2 + tap];
            float w40 = W1t[(o * 41 + 40) * 2 + tap];
            v = f2bf(W1t[(o * 41 + c) * 2 + tap] + (w40 - S) * 0.025f);
        }
        wu[W1T_U + r] = v;
    } else if (n < 112640) {               // W2
        int r = n - 61440;
        int tap = r / 25600, m = r % 25600;
        int ct = m / 2560, m2 = m % 2560;
        int kp = m2 / 128, col = (m2 % 128) / 8, i = m2 % 8;
        int o = ct * 16 + col, c = kp * 8 + i;
        wu[W2_U + r] = f2bf(W2[(o * 160 + c) * 2 + tap]);
    } else if (n < 112800) {               // b1 combined
        int o = n - 112640;
        wf[B1C_F + o] = b1f[o] + b1t[o];
    } else if (n < 112960) {               // b2 copy
        int o = n - 112800;
        wf[B2C_F + o] = b2[o];
    }
}

__global__ __launch_bounds__(NTH) void td_main(
    const float* __restrict__ x,
    const float* __restrict__ feat,
    const unsigned short* __restrict__ wu,
    const float* __restrict__ wf,
    float* __restrict__ out)
{
    // r7-proven strides. Row anchors: feat/e row r <-> t = t0-2+r;
    // hid row h <-> t = t0-1+h (1-row halo). Block pipelines 4 consecutive tiles.
    __shared__ __align__(16) unsigned short s_feat[65 * 136];
    __shared__ __align__(16) unsigned short s_e   [65 * 72];  // cols 0..39 = e, 40..63 zero
    __shared__ __align__(16) unsigned short s_hid [64 * 168];

    const int tid  = threadIdx.x;
    const int b    = blockIdx.y;
    const int wid  = tid >> 6;    // 0..9 = ct (wave-stationary output col-tile)
    const int lane = tid & 63;
    const int lr   = lane & 15;   // time-row within tile (swapped-operand D layout)
    const int lk   = lane >> 4;   // k-group / channel-quad group
    const int ct   = wid;
    const int cbase = lk * 8;

    const float4* feat4 = (const float4*)feat;
    const float4* x4    = (const float4*)x;

    // ---- weight prologue: BOTH stages, straight-line, AGPR-stationary,
    // amortized over 4 time-tiles ----
    short8 wB0[6], wB1[6];   // s=0..3 feat-taps, s=4..5 tenv-taps
    {
        const unsigned short* bf0 = wu + W1F_U + ct * 2048 + lk * 128 + lr * 8;
        const unsigned short* bt0 = wu + W1T_U + ct * 1024 + lk * 128 + lr * 8;
#pragma unroll
        for (int s = 0; s < 4; ++s) {
            wB0[s] = *(const short8*)(bf0 + s * 512);
            wB1[s] = *(const short8*)(bf0 + 20480 + s * 512);
        }
#pragma unroll
        for (int s = 0; s < 2; ++s) {
            wB0[4 + s] = *(const short8*)(bt0 + s * 512);
            wB1[4 + s] = *(const short8*)(bt0 + 10240 + s * 512);
        }
    }
    short8 wC0[5], wC1[5];
    {
        const unsigned short* b2p = wu + W2_U + ct * 2560 + lk * 128 + lr * 8;
#pragma unroll
        for (int s = 0; s < 5; ++s) {
            wC0[s] = *(const short8*)(b2p + s * 512);
            wC1[s] = *(const short8*)(b2p + 25600 + s * 512);
        }
    }
    const float4 bias1 = *(const float4*)&wf[B1C_F + ct * 16 + lk * 4];
    const float4 bias2 = *(const float4*)&wf[B2C_F + ct * 16 + lk * 4];

    // ---- phase lambdas (r19 bodies, parameterized by tile origin t0) ----
    auto STAGE = [&](int t0) {
        for (int idx = tid; idx < 65 * 32; idx += NTH) {
            int r = idx >> 5, c4 = idx & 31;
            int t = t0 - 2 + r;
            float4 v = make_float4(0.f, 0.f, 0.f, 0.f);
            if (t >= 0 && t < TS) v = feat4[((size_t)b * TS + t) * 32 + c4];
            ushort4 h;
            h.x = f2bf(v.x); h.y = f2bf(v.y); h.z = f2bf(v.z); h.w = f2bf(v.w);
            *(ushort4*)&s_feat[r * 136 + c4 * 4] = h;
        }
        for (int idx = tid; idx < 65 * 40; idx += NTH) {
            int r = idx / 40, g = idx - r * 40;
            int t = t0 - 2 + r;
            // OOR rows MUST be exactly 0: pad rows feed tap0 of hid row th=0.
            unsigned short u = 0;
            if (t >= 0 && t < TS) {
                float4 v = x4[((size_t)b * NN + (size_t)t * 160 + g * 4) >> 2];
                float m = 0.25f * (fabsf(v.x) + fabsf(v.y) + fabsf(v.z) + fabsf(v.w));
                u = f2bf(__logf(m + EPS_LOG));
            }
            s_e[r * 72 + g] = u;
        }
        if (tid < 65 * 3) {   // zero pad cols 40..63 (keep MFMA operands finite)
            int r = tid / 3, sgm = tid - r * 3;
            short8 z = {0, 0, 0, 0, 0, 0, 0, 0};
            *(short8*)&s_e[r * 72 + 40 + sgm * 8] = z;
        }
    };

    auto STAGEB = [&](int t0) {
#pragma unroll 2
        for (int tile = 0; tile < 4; ++tile) {
            const int rB = tile * 16 + lr;
            const unsigned short* f0 = &s_feat[rB * 136 + cbase];
            const unsigned short* e0 = &s_e[rB * 72 + cbase];
            f32x4 acc0 = {0.f, 0.f, 0.f, 0.f};
            f32x4 acc1 = {0.f, 0.f, 0.f, 0.f};
#pragma unroll
            for (int s = 0; s < 4; ++s) {
                short8 a0 = *(const short8*)(f0 + 32 * s);          // feat[t-1]
                short8 a1 = *(const short8*)(f0 + 136 + 32 * s);    // feat[t]
                acc0 = __builtin_amdgcn_mfma_f32_16x16x32_bf16(wB0[s], a0, acc0, 0, 0, 0);
                acc1 = __builtin_amdgcn_mfma_f32_16x16x32_bf16(wB1[s], a1, acc1, 0, 0, 0);
            }
#pragma unroll
            for (int s = 0; s < 2; ++s) {
                short8 a0 = *(const short8*)(e0 + 32 * s);
                short8 a1 = *(const short8*)(e0 + 72 + 32 * s);
                acc0 = __builtin_amdgcn_mfma_f32_16x16x32_bf16(wB0[4 + s], a0, acc0, 0, 0, 0);
                acc1 = __builtin_amdgcn_mfma_f32_16x16x32_bf16(wB1[4 + s], a1, acc1, 0, 0, 0);
            }
            const int th = t0 - 1 + rB;   // lane-uniform
            ushort4 pk;
            {
                float v0 = acc0[0] + acc1[0] + bias1.x; v0 = v0 >= 0.f ? v0 : 0.2f * v0;
                float v1 = acc0[1] + acc1[1] + bias1.y; v1 = v1 >= 0.f ? v1 : 0.2f * v1;
                float v2 = acc0[2] + acc1[2] + bias1.z; v2 = v2 >= 0.f ? v2 : 0.2f * v2;
                float v3 = acc0[3] + acc1[3] + bias1.w; v3 = v3 >= 0.f ? v3 : 0.2f * v3;
                pk.x = f2bf(v0); pk.y = f2bf(v1); pk.z = f2bf(v2); pk.w = f2bf(v3);
            }
            if (th < 0) pk = make_ushort4(0, 0, 0, 0);
            *(ushort4*)&s_hid[rB * 168 + ct * 16 + lk * 4] = pk;
        }
    };

    auto STAGEC = [&](int t0) {
#pragma unroll 2
        for (int tile = 0; tile < 4; ++tile) {
            const int rC  = tile * 16 + lr;
            const int rCc = rC < 63 ? rC : 62;   // lane (tile3,lr15) masked; keep in bounds
            const unsigned short* hb = &s_hid[rCc * 168 + cbase];
            f32x4 acc0 = {0.f, 0.f, 0.f, 0.f};
            f32x4 acc1 = {0.f, 0.f, 0.f, 0.f};
#pragma unroll
            for (int s = 0; s < 5; ++s) {
                short8 a0 = *(const short8*)(hb + 32 * s);          // hid[t-1]
                short8 a1 = *(const short8*)(hb + 168 + 32 * s);    // hid[t]
                acc0 = __builtin_amdgcn_mfma_f32_16x16x32_bf16(wC0[s], a0, acc0, 0, 0, 0);
                acc1 = __builtin_amdgcn_mfma_f32_16x16x32_bf16(wC1[s], a1, acc1, 0, 0, 0);
            }
            const int t = t0 + rC;   // lane-uniform
            if (rC < MB && t < TS) {
                size_t off = (size_t)b * NN + (size_t)t * 160 + ct * 16 + lk * 4;
                float4 xv = *(const float4*)&x[off];
                float4 yv;
                yv.x = __expf(acc0[0] + acc1[0] + bias2.x) * xv.x;
                yv.y = __expf(acc0[1] + acc1[1] + bias2.y) * xv.y;
                yv.z = __expf(acc0[2] + acc1[2] + bias2.z) * xv.z;
                yv.w = __expf(acc0[3] + acc1[3] + bias2.w) * xv.w;
                *(float4*)&out[off] = yv;
            }
        }
    };

    // ---- 4-tile software pipeline: stage(i+1) overlaps C(i) ----
    const int tb0 = blockIdx.x * TPB;
    int t0 = tb0 * MB;

    STAGE(t0);
    __syncthreads();          // feat/e(0) staged
    STAGEB(t0);

#pragma unroll 1
    for (int i = 0; i < TPB; ++i) {
        __syncthreads();      // hid(i) ready; B(i)'s feat-reads done
        int t0n = (tb0 + i + 1) * MB;
        if (i + 1 < TPB) STAGE(t0n);   // issue next tile's HBM loads early...
        STAGEC(t0);                    // ...their latency hides under C's MFMAs
        if (i + 1 < TPB) {
            __syncthreads();  // feat/e(i+1) staged AND C(i)'s hid-reads done
            STAGEB(t0n);
            t0 = t0n;
        }
    }
}

extern "C" void kernel_launch(void* const* d_in, const int* in_sizes, int n_in,
                              void* d_out, int out_size, void* d_ws, size_t ws_size,
                              hipStream_t stream) {
    const float* x    = (const float*)d_in[0];
    const float* feat = (const float*)d_in[1];
    const float* W1f  = (const float*)d_in[2];
    const float* b1f  = (const float*)d_in[3];
    const float* W1t  = (const float*)d_in[4];
    const float* b1t  = (const float*)d_in[5];
    const float* W2   = (const float*)d_in[6];
    const float* b2   = (const float*)d_in[7];
    float* out = (float*)d_out;

    repack<<<(112960 + 255) / 256, 256, 0, stream>>>(W1f, b1f, W1t, b1t, W2, b2, d_ws);
    td_main<<<dim3(GX, BB), NTH, 0, stream>>>(
        x, feat, (const unsigned short*)d_ws, (const float*)d_ws, out);
}

// Round 23
// 81.016 us; speedup vs baseline: 1.7387x; 1.0108x over previous
//
#include <hip/hip_runtime.h>

typedef __attribute__((ext_vector_type(8))) short short8;
typedef __attribute__((ext_vector_type(4))) float f32x4;

#define BB 64
#define TS 2000
#define NN (TS*160)
#define MB 63            // 63 outputs/tile: 64 hid rows = 63 + 1 halo
#define TPB 8            // time-tiles per block (pipelined)
#define GX 4             // grid.x: 4 * 8 = 32 tiles; grid = 256 blocks = 1/CU
#define NTH 640          // 10 waves: wave = output col-tile ct
#define EPS_LOG 1.52587890625e-05f   // 2^-16

// ws layout: ushort (bf16) region then float region
#define W1F_U 0          // 40960 ushorts: [tap][ct10][kp16][col16][8]
#define W1T_U 40960      // 20480 ushorts: [tap][ct10][kp8][col16][8]  (MEAN-FOLDED W1teff; k>=40 zero)
#define W2_U  61440      // 51200 ushorts: [tap][ct10][kp20][col16][8]
#define B1C_F 56320      // float idx: b1f+b1t (160)
#define B2C_F 56480      // float idx: b2 (160)

__device__ __forceinline__ unsigned short f2bf(float f) {
    union { float f; unsigned u; } v; v.f = f;
    unsigned r = v.u + 0x7FFF + ((v.u >> 16) & 1);   // RNE
    return (unsigned short)(r >> 16);
}

__global__ void repack(const float* __restrict__ W1f, const float* __restrict__ b1f,
                       const float* __restrict__ W1t, const float* __restrict__ b1t,
                       const float* __restrict__ W2,  const float* __restrict__ b2,
                       void* wsv) {
    unsigned short* wu = (unsigned short*)wsv;
    float* wf = (float*)wsv;
    int n = blockIdx.x * 256 + threadIdx.x;
    if (n < 40960) {                       // W1f
        int tap = n / 20480, m = n % 20480;
        int ct = m / 2048, m2 = m % 2048;
        int kp = m2 / 128, col = (m2 % 128) / 8, i = m2 % 8;
        int o = ct * 16 + col, c = kp * 8 + i;
        wu[W1F_U + n] = f2bf(W1f[(o * 128 + c) * 2 + tap]);
    } else if (n < 61440) {                // W1teff: mean-folded, K padded to 64
        int r = n - 40960;
        int tap = r / 10240, m = r % 10240;
        int ct = m / 1024, m2 = m % 1024;
        int kp = m2 / 128, col = (m2 % 128) / 8, i = m2 % 8;
        int o = ct * 16 + col, c = kp * 8 + i;
        unsigned short v = 0;
        if (c < 40) {
            float S = 0.f;
            for (int g = 0; g < 40; ++g) S += W1t[(o * 41 + g) * 2 + tap];
            float w40 = W1t[(o * 41 + 40) * 2 + tap];
            v = f2bf(W1t[(o * 41 + c) * 2 + tap] + (w40 - S) * 0.025f);
        }
        wu[W1T_U + r] = v;
    } else if (n < 112640) {               // W2
        int r = n - 61440;
        int tap = r / 25600, m = r % 25600;
        int ct = m / 2560, m2 = m % 2560;
        int kp = m2 / 128, col = (m2 % 128) / 8, i = m2 % 8;
        int o = ct * 16 + col, c = kp * 8 + i;
        wu[W2_U + r] = f2bf(W2[(o * 160 + c) * 2 + tap]);
    } else if (n < 112800) {               // b1 combined
        int o = n - 112640;
        wf[B1C_F + o] = b1f[o] + b1t[o];
    } else if (n < 112960) {               // b2 copy
        int o = n - 112800;
        wf[B2C_F + o] = b2[o];
    }
}

__global__ __launch_bounds__(NTH) void td_main(
    const float* __restrict__ x,
    const float* __restrict__ feat,
    const unsigned short* __restrict__ wu,
    const float* __restrict__ wf,
    float* __restrict__ out)
{
    // r7-proven strides. Row anchors: feat/e row r <-> t = t0-2+r;
    // hid row h <-> t = t0-1+h (1-row halo). Block pipelines 8 consecutive tiles.
    __shared__ __align__(16) unsigned short s_feat[65 * 136];
    __shared__ __align__(16) unsigned short s_e   [65 * 72];  // cols 0..39 = e, 40..63 zero
    __shared__ __align__(16) unsigned short s_hid [64 * 168];

    const int tid  = threadIdx.x;
    const int b    = blockIdx.y;
    const int wid  = tid >> 6;    // 0..9 = ct (wave-stationary output col-tile)
    const int lane = tid & 63;
    const int lr   = lane & 15;   // time-row within tile (swapped-operand D layout)
    const int lk   = lane >> 4;   // k-group / channel-quad group
    const int ct   = wid;
    const int cbase = lk * 8;

    const float4* feat4 = (const float4*)feat;
    const float4* x4    = (const float4*)x;

    // ---- weight prologue: BOTH stages, straight-line, AGPR-stationary,
    // amortized over 8 time-tiles ----
    short8 wB0[6], wB1[6];   // s=0..3 feat-taps, s=4..5 tenv-taps
    {
        const unsigned short* bf0 = wu + W1F_U + ct * 2048 + lk * 128 + lr * 8;
        const unsigned short* bt0 = wu + W1T_U + ct * 1024 + lk * 128 + lr * 8;
#pragma unroll
        for (int s = 0; s < 4; ++s) {
            wB0[s] = *(const short8*)(bf0 + s * 512);
            wB1[s] = *(const short8*)(bf0 + 20480 + s * 512);
        }
#pragma unroll
        for (int s = 0; s < 2; ++s) {
            wB0[4 + s] = *(const short8*)(bt0 + s * 512);
            wB1[4 + s] = *(const short8*)(bt0 + 10240 + s * 512);
        }
    }
    short8 wC0[5], wC1[5];
    {
        const unsigned short* b2p = wu + W2_U + ct * 2560 + lk * 128 + lr * 8;
#pragma unroll
        for (int s = 0; s < 5; ++s) {
            wC0[s] = *(const short8*)(b2p + s * 512);
            wC1[s] = *(const short8*)(b2p + 25600 + s * 512);
        }
    }
    const float4 bias1 = *(const float4*)&wf[B1C_F + ct * 16 + lk * 4];
    const float4 bias2 = *(const float4*)&wf[B2C_F + ct * 16 + lk * 4];

    // ---- phase lambdas (r19 bodies, parameterized by tile origin t0) ----
    auto STAGE = [&](int t0) {
        for (int idx = tid; idx < 65 * 32; idx += NTH) {
            int r = idx >> 5, c4 = idx & 31;
            int t = t0 - 2 + r;
            float4 v = make_float4(0.f, 0.f, 0.f, 0.f);
            if (t >= 0 && t < TS) v = feat4[((size_t)b * TS + t) * 32 + c4];
            ushort4 h;
            h.x = f2bf(v.x); h.y = f2bf(v.y); h.z = f2bf(v.z); h.w = f2bf(v.w);
            *(ushort4*)&s_feat[r * 136 + c4 * 4] = h;
        }
        for (int idx = tid; idx < 65 * 40; idx += NTH) {
            int r = idx / 40, g = idx - r * 40;
            int t = t0 - 2 + r;
            // OOR rows MUST be exactly 0: pad rows feed tap0 of hid row th=0.
            unsigned short u = 0;
            if (t >= 0 && t < TS) {
                float4 v = x4[((size_t)b * NN + (size_t)t * 160 + g * 4) >> 2];
                float m = 0.25f * (fabsf(v.x) + fabsf(v.y) + fabsf(v.z) + fabsf(v.w));
                u = f2bf(__logf(m + EPS_LOG));
            }
            s_e[r * 72 + g] = u;
        }
        if (tid < 65 * 3) {   // zero pad cols 40..63 (keep MFMA operands finite)
            int r = tid / 3, sgm = tid - r * 3;
            short8 z = {0, 0, 0, 0, 0, 0, 0, 0};
            *(short8*)&s_e[r * 72 + 40 + sgm * 8] = z;
        }
    };

    auto STAGEB = [&](int t0) {
#pragma unroll 2
        for (int tile = 0; tile < 4; ++tile) {
            const int rB = tile * 16 + lr;
            const unsigned short* f0 = &s_feat[rB * 136 + cbase];
            const unsigned short* e0 = &s_e[rB * 72 + cbase];
            f32x4 acc0 = {0.f, 0.f, 0.f, 0.f};
            f32x4 acc1 = {0.f, 0.f, 0.f, 0.f};
#pragma unroll
            for (int s = 0; s < 4; ++s) {
                short8 a0 = *(const short8*)(f0 + 32 * s);          // feat[t-1]
                short8 a1 = *(const short8*)(f0 + 136 + 32 * s);    // feat[t]
                acc0 = __builtin_amdgcn_mfma_f32_16x16x32_bf16(wB0[s], a0, acc0, 0, 0, 0);
                acc1 = __builtin_amdgcn_mfma_f32_16x16x32_bf16(wB1[s], a1, acc1, 0, 0, 0);
            }
#pragma unroll
            for (int s = 0; s < 2; ++s) {
                short8 a0 = *(const short8*)(e0 + 32 * s);
                short8 a1 = *(const short8*)(e0 + 72 + 32 * s);
                acc0 = __builtin_amdgcn_mfma_f32_16x16x32_bf16(wB0[4 + s], a0, acc0, 0, 0, 0);
                acc1 = __builtin_amdgcn_mfma_f32_16x16x32_bf16(wB1[4 + s], a1, acc1, 0, 0, 0);
            }
            const int th = t0 - 1 + rB;   // lane-uniform
            ushort4 pk;
            {
                float v0 = acc0[0] + acc1[0] + bias1.x; v0 = v0 >= 0.f ? v0 : 0.2f * v0;
                float v1 = acc0[1] + acc1[1] + bias1.y; v1 = v1 >= 0.f ? v1 : 0.2f * v1;
                float v2 = acc0[2] + acc1[2] + bias1.z; v2 = v2 >= 0.f ? v2 : 0.2f * v2;
                float v3 = acc0[3] + acc1[3] + bias1.w; v3 = v3 >= 0.f ? v3 : 0.2f * v3;
                pk.x = f2bf(v0); pk.y = f2bf(v1); pk.z = f2bf(v2); pk.w = f2bf(v3);
            }
            if (th < 0) pk = make_ushort4(0, 0, 0, 0);
            *(ushort4*)&s_hid[rB * 168 + ct * 16 + lk * 4] = pk;
        }
    };

    auto STAGEC = [&](int t0) {
#pragma unroll 2
        for (int tile = 0; tile < 4; ++tile) {
            const int rC  = tile * 16 + lr;
            const int rCc = rC < 63 ? rC : 62;   // lane (tile3,lr15) masked; keep in bounds
            const unsigned short* hb = &s_hid[rCc * 168 + cbase];
            f32x4 acc0 = {0.f, 0.f, 0.f, 0.f};
            f32x4 acc1 = {0.f, 0.f, 0.f, 0.f};
#pragma unroll
            for (int s = 0; s < 5; ++s) {
                short8 a0 = *(const short8*)(hb + 32 * s);          // hid[t-1]
                short8 a1 = *(const short8*)(hb + 168 + 32 * s);    // hid[t]
                acc0 = __builtin_amdgcn_mfma_f32_16x16x32_bf16(wC0[s], a0, acc0, 0, 0, 0);
                acc1 = __builtin_amdgcn_mfma_f32_16x16x32_bf16(wC1[s], a1, acc1, 0, 0, 0);
            }
            const int t = t0 + rC;   // lane-uniform
            if (rC < MB && t < TS) {
                size_t off = (size_t)b * NN + (size_t)t * 160 + ct * 16 + lk * 4;
                float4 xv = *(const float4*)&x[off];
                float4 yv;
                yv.x = __expf(acc0[0] + acc1[0] + bias2.x) * xv.x;
                yv.y = __expf(acc0[1] + acc1[1] + bias2.y) * xv.y;
                yv.z = __expf(acc0[2] + acc1[2] + bias2.z) * xv.z;
                yv.w = __expf(acc0[3] + acc1[3] + bias2.w) * xv.w;
                *(float4*)&out[off] = yv;
            }
        }
    };

    // ---- 8-tile software pipeline: stage(i+1) overlaps C(i) ----
    const int tb0 = blockIdx.x * TPB;
    int t0 = tb0 * MB;

    STAGE(t0);
    __syncthreads();          // feat/e(0) staged
    STAGEB(t0);

#pragma unroll 1
    for (int i = 0; i < TPB; ++i) {
        __syncthreads();      // hid(i) ready; B(i)'s feat-reads done
        int t0n = (tb0 + i + 1) * MB;
        if (i + 1 < TPB) STAGE(t0n);   // issue next tile's HBM loads early...
        STAGEC(t0);                    // ...their latency hides under C's MFMAs
        if (i + 1 < TPB) {
            __syncthreads();  // feat/e(i+1) staged AND C(i)'s hid-reads done
            STAGEB(t0n);
            t0 = t0n;
        }
    }
}

extern "C" void kernel_launch(void* const* d_in, const int* in_sizes, int n_in,
                              void* d_out, int out_size, void* d_ws, size_t ws_size,
                              hipStream_t stream) {
    const float* x    = (const float*)d_in[0];
    const float* feat = (const float*)d_in[1];
    const float* W1f  = (const float*)d_in[2];
    const float* b1f  = (const float*)d_in[3];
    const float* W1t  = (const float*)d_in[4];
    const float* b1t  = (const float*)d_in[5];
    const float* W2   = (const float*)d_in[6];
    const float* b2   = (const float*)d_in[7];
    float* out = (float*)d_out;

    repack<<<(112960 + 255) / 256, 256, 0, stream>>>(W1f, b1f, W1t, b1t, W2, b2, d_ws);
    td_main<<<dim3(GX, BB), NTH, 0, stream>>>(
        x, feat, (const unsigned short*)d_ws, (const float*)d_ws, out);
}